// Round 8
// baseline (320.623 us; speedup 1.0000x reference)
//
#include <hip/hip_runtime.h>

#define N_NODES 100000
#define N_EDGES 1600000
#define D 128
#define N_STRIPS (N_NODES / 32)     // 3125

#define BSH   9                     // coarse bucket = col >> 9 (512 nodes/bucket)
#define NBKT  196                   // ceil(100000 / 512)
#define P_BLK 160                   // partition blocks; EPB = 10000 exactly
#define EPB   (N_EDGES / P_BLK)
#define CAST_BLK 256                // cast sub-grid blocks (1024 thr each)

typedef __bf16 bf16x4 __attribute__((ext_vector_type(4)));
typedef __bf16 bf16x8 __attribute__((ext_vector_type(8)));
typedef float  f32x4  __attribute__((ext_vector_type(4)));

// ---- fused: cast x,W to bf16  +  per-block coarse histogram ----
__global__ __launch_bounds__(1024) void k_prep(const float4* __restrict__ x4,
                                               const float4* __restrict__ w4,
                                               bf16x4* __restrict__ xb4,
                                               bf16x4* __restrict__ wb4,
                                               const int* __restrict__ col,
                                               int* __restrict__ bhist) {
    __shared__ int lh[NBKT];
    int b = blockIdx.x, tid = threadIdx.x;
    if (b < P_BLK) {                               // histogram part
        if (tid < NBKT) lh[tid] = 0;
        __syncthreads();
        int e0 = b * EPB;
        for (int e = e0 + tid; e < e0 + EPB; e += 1024)
            atomicAdd(&lh[col[e] >> BSH], 1);
        __syncthreads();
        if (tid < NBKT) bhist[tid * P_BLK + b] = lh[tid];
    } else {                                       // cast part
        int cb = b - P_BLK;
        const int total = N_NODES * D / 4;
        for (int i = cb * 1024 + tid; i < total; i += CAST_BLK * 1024) {
            float4 v = x4[i];
            bf16x4 o;
            o[0] = (__bf16)v.x; o[1] = (__bf16)v.y; o[2] = (__bf16)v.z; o[3] = (__bf16)v.w;
            xb4[i] = o;
        }
        if (cb == 0) {
            for (int i = tid; i < (D * D) / 4; i += 1024) {
                float4 u = w4[i];
                bf16x4 p;
                p[0] = (__bf16)u.x; p[1] = (__bf16)u.y; p[2] = (__bf16)u.z; p[3] = (__bf16)u.w;
                wb4[i] = p;
            }
        }
    }
}

// ---- per-bucket exclusive scan over the 160 block counts; totals -> gtot ----
__global__ __launch_bounds__(256) void k_bscan(int* __restrict__ bhist,
                                               int* __restrict__ gtot) {
    __shared__ int buf[256];
    int k = blockIdx.x, t = threadIdx.x;
    int v = (t < P_BLK) ? bhist[k * P_BLK + t] : 0;
    buf[t] = v;
    __syncthreads();
    for (int off = 1; off < 256; off <<= 1) {
        int u = (t >= off) ? buf[t - off] : 0;
        __syncthreads();
        buf[t] += u;
        __syncthreads();
    }
    if (t < P_BLK) bhist[k * P_BLK + t] = buf[t] - v;   // exclusive
    if (t == 255) gtot[k] = buf[255];
}

// ---- direct scatter; computes gstart scan locally; zero global atomics ----
__global__ __launch_bounds__(1024) void k_cscatter(const int* __restrict__ row,
                                                   const int* __restrict__ col,
                                                   const int* __restrict__ bhist,
                                                   const int* __restrict__ gtot,
                                                   unsigned* __restrict__ grec) {
    __shared__ int sbuf[256];
    __shared__ int cur[NBKT];
    int b = blockIdx.x, t = threadIdx.x;
    int v = 0;
    if (t < 256) { v = (t < NBKT) ? gtot[t] : 0; sbuf[t] = v; }
    __syncthreads();
    for (int off = 1; off < 256; off <<= 1) {
        int u = 0;
        if (t < 256 && t >= off) u = sbuf[t - off];
        __syncthreads();
        if (t < 256) sbuf[t] += u;
        __syncthreads();
    }
    if (t < NBKT) cur[t] = (sbuf[t] - v) + bhist[t * P_BLK + b];
    __syncthreads();
    int e0 = b * EPB;
    for (int e = e0 + t; e < e0 + EPB; e += 1024) {
        int c = col[e];
        unsigned rec = ((unsigned)row[e] << BSH) | (unsigned)(c & ((1 << BSH) - 1));
        int pos = atomicAdd(&cur[c >> BSH], 1);
        grec[pos] = rec;
    }
}

// ---- per-bucket fine sort in LDS; emits deg/dis/start/srcs ----
__global__ __launch_bounds__(1024) void k_fine(const unsigned* __restrict__ grec,
                                               const int* __restrict__ gtot,
                                               int* __restrict__ deg,
                                               float* __restrict__ dis,
                                               int* __restrict__ start,
                                               int* __restrict__ srcs) {
    __shared__ int fh[512];
    __shared__ int fscan[512];
    __shared__ int sbuf[256];
    __shared__ int gs_sh;
    int b = blockIdx.x;
    int tid = threadIdx.x;
    int cnt = gtot[b];
    // local exclusive scan of gtot -> gs for this bucket
    int v0 = 0;
    if (tid < 256) { v0 = (tid < NBKT) ? gtot[tid] : 0; sbuf[tid] = v0; }
    if (tid < 512) fh[tid] = 0;
    __syncthreads();
    for (int off = 1; off < 256; off <<= 1) {
        int u = 0;
        if (tid < 256 && tid >= off) u = sbuf[tid - off];
        __syncthreads();
        if (tid < 256) sbuf[tid] += u;
        __syncthreads();
    }
    if (tid == b) gs_sh = sbuf[tid] - v0;
    __syncthreads();
    int gs = gs_sh;
    for (int i = tid; i < cnt; i += 1024)
        atomicAdd(&fh[grec[gs + i] & 511], 1);
    __syncthreads();
    int v = 0;
    if (tid < 512) { v = fh[tid]; fscan[tid] = v; }
    __syncthreads();
    for (int off = 1; off < 512; off <<= 1) {
        int u = 0;
        if (tid < 512 && tid >= off) u = fscan[tid - off];
        __syncthreads();
        if (tid < 512) fscan[tid] += u;
        __syncthreads();
    }
    if (tid < 512) {
        int excl = fscan[tid] - v;
        int node = (b << BSH) + tid;
        if (node < N_NODES) {
            deg[node] = v;
            dis[node] = rsqrtf((float)v + 1.0f);
            start[node] = gs + excl;
        }
        fh[tid] = excl;                       // -> cursors
    }
    __syncthreads();
    for (int i = tid; i < cnt; i += 1024) {
        unsigned r = grec[gs + i];
        int pos = atomicAdd(&fh[r & 511], 1);
        srcs[gs + pos] = (int)(r >> BSH);
    }
}

// ---- fused aggregate + MFMA transform; block = 4 waves = 32 nodes ----
// Wave w aggregates nodes m0+8w..m0+8w+7 into LDS tile Vl (stride 132:
// <=2-way bank aliasing, free), then the block computes
// out = relu(Vl @ W^T + bias) for its 32 rows. No agg round-trip to HBM.
__global__ __launch_bounds__(256) void k_aggtrans(const int* __restrict__ srcs,
                                                  const int* __restrict__ start,
                                                  const int* __restrict__ deg,
                                                  const __bf16* __restrict__ xb,
                                                  const float* __restrict__ dis,
                                                  const __bf16* __restrict__ wb,
                                                  const float* __restrict__ bias,
                                                  float* __restrict__ out) {
    __shared__ float Vl[32 * 132];
    int t = threadIdx.x;
    int wave = t >> 6, lane = t & 63;
    int m0 = blockIdx.x * 32;

    for (int q = 0; q < 8; ++q) {
        int nl = wave * 8 + q;
        int node = m0 + nl;
        int s = start[node];
        int n = deg[node];
        float dc = dis[node];
        unsigned u0 = ((const unsigned*)(xb + (size_t)node * D))[lane];
        float accx = __uint_as_float(u0 << 16) * dc * dc;
        float accy = __uint_as_float(u0 & 0xFFFF0000u) * dc * dc;

        for (int base = 0; base < n; base += 64) {
            int m = n - base; if (m > 64) m = 64;
            int   src_l = 0;
            float nr_l  = 0.f;
            if (lane < m) {
                src_l = srcs[s + base + lane];
                nr_l  = dis[src_l] * dc;
            }
            int i = 0;
            for (; i + 8 <= m; i += 8) {
                int   sv[8];
                float nv[8];
                unsigned av[8];
                #pragma unroll
                for (int j = 0; j < 8; ++j) {
                    sv[j] = __shfl(src_l, i + j);
                    nv[j] = __shfl(nr_l, i + j);
                }
                #pragma unroll
                for (int j = 0; j < 8; ++j)
                    av[j] = ((const unsigned*)(xb + (size_t)sv[j] * D))[lane];
                #pragma unroll
                for (int j = 0; j < 8; ++j) {
                    accx += __uint_as_float(av[j] << 16) * nv[j];
                    accy += __uint_as_float(av[j] & 0xFFFF0000u) * nv[j];
                }
            }
            for (; i + 4 <= m; i += 4) {
                int   sv[4];
                float nv[4];
                unsigned av[4];
                #pragma unroll
                for (int j = 0; j < 4; ++j) {
                    sv[j] = __shfl(src_l, i + j);
                    nv[j] = __shfl(nr_l, i + j);
                }
                #pragma unroll
                for (int j = 0; j < 4; ++j)
                    av[j] = ((const unsigned*)(xb + (size_t)sv[j] * D))[lane];
                #pragma unroll
                for (int j = 0; j < 4; ++j) {
                    accx += __uint_as_float(av[j] << 16) * nv[j];
                    accy += __uint_as_float(av[j] & 0xFFFF0000u) * nv[j];
                }
            }
            for (; i < m; ++i) {
                int   si = __shfl(src_l, i);
                float ni = __shfl(nr_l, i);
                unsigned a = ((const unsigned*)(xb + (size_t)si * D))[lane];
                accx += __uint_as_float(a << 16) * ni;
                accy += __uint_as_float(a & 0xFFFF0000u) * ni;
            }
        }
        float2 r; r.x = accx; r.y = accy;
        ((float2*)(Vl + nl * 132))[lane] = r;
    }
    __syncthreads();

    // transform: A-frags from Vl (fp32 -> bf16 in-reg), B from global wb (L1)
    int l15 = lane & 15;
    int kq  = lane >> 4;
    bf16x8 a[2][4];
    #pragma unroll
    for (int mt = 0; mt < 2; ++mt) {
        const float* ap = Vl + (mt * 16 + l15) * 132 + kq * 8;
        #pragma unroll
        for (int ks = 0; ks < 4; ++ks) {
            float4 lo = *(const float4*)(ap + ks * 32);
            float4 hi = *(const float4*)(ap + ks * 32 + 4);
            bf16x8 tt;
            tt[0] = (__bf16)lo.x; tt[1] = (__bf16)lo.y;
            tt[2] = (__bf16)lo.z; tt[3] = (__bf16)lo.w;
            tt[4] = (__bf16)hi.x; tt[5] = (__bf16)hi.y;
            tt[6] = (__bf16)hi.z; tt[7] = (__bf16)hi.w;
            a[mt][ks] = tt;
        }
    }

    f32x4 acc[2][8] = {};
    #pragma unroll
    for (int ks = 0; ks < 4; ++ks) {
        #pragma unroll
        for (int nt = 0; nt < 8; ++nt) {
            bf16x8 b = *(const bf16x8*)(wb + (size_t)(nt * 16 + l15) * D + ks * 32 + kq * 8);
            acc[0][nt] = __builtin_amdgcn_mfma_f32_16x16x32_bf16(a[0][ks], b, acc[0][nt], 0, 0, 0);
            acc[1][nt] = __builtin_amdgcn_mfma_f32_16x16x32_bf16(a[1][ks], b, acc[1][nt], 0, 0, 0);
        }
    }

    #pragma unroll
    for (int nt = 0; nt < 8; ++nt) {
        int colj = nt * 16 + l15;
        float bj = bias[colj];
        #pragma unroll
        for (int mt = 0; mt < 2; ++mt) {
            #pragma unroll
            for (int r = 0; r < 4; ++r) {
                int rowi = m0 + mt * 16 + kq * 4 + r;
                out[(size_t)rowi * D + colj] = fmaxf(acc[mt][nt][r] + bj, 0.f);
            }
        }
    }
}

extern "C" void kernel_launch(void* const* d_in, const int* in_sizes, int n_in,
                              void* d_out, int out_size, void* d_ws, size_t ws_size,
                              hipStream_t stream) {
    const float* x    = (const float*)d_in[0];
    const int*   ei   = (const int*)d_in[1];    // [2, E]: row then col
    const float* w    = (const float*)d_in[2];
    const float* bias = (const float*)d_in[3];
    float* out = (float*)d_out;

    char* ws = (char*)d_ws;
    int*      deg    = (int*)ws;              ws += N_NODES * 4;
    float*    dis    = (float*)ws;            ws += N_NODES * 4;
    int*      start  = (int*)ws;              ws += N_NODES * 4;
    int*      bhist  = (int*)ws;              ws += NBKT * P_BLK * 4;
    int*      gtot   = (int*)ws;              ws += 256 * 4;
    __bf16*   wb     = (__bf16*)ws;           ws += D * D * 2;
    unsigned* grec   = (unsigned*)ws;         ws += (size_t)N_EDGES * 4;
    int*      srcs   = (int*)ws;              ws += (size_t)N_EDGES * 4;
    __bf16*   xb     = (__bf16*)ws;           // N_NODES * D * 2 = 25.6 MB

    const int* row = ei;
    const int* col = ei + N_EDGES;

    k_prep    <<<P_BLK + CAST_BLK, 1024, 0, stream>>>(
                  (const float4*)x, (const float4*)w, (bf16x4*)xb, (bf16x4*)wb,
                  col, bhist);
    k_bscan   <<<NBKT, 256, 0, stream>>>(bhist, gtot);
    k_cscatter<<<P_BLK, 1024, 0, stream>>>(row, col, bhist, gtot, grec);
    k_fine    <<<NBKT, 1024, 0, stream>>>(grec, gtot, deg, dis, start, srcs);
    k_aggtrans<<<N_STRIPS, 256, 0, stream>>>(srcs, start, deg, xb, dis, wb, bias, out);
}